// Round 1
// baseline (2250.218 us; speedup 1.0000x reference)
//
#include <hip/hip_runtime.h>

// ---------------------------------------------------------------------------
// Seq2Seq (bi-LSTM encoder + attention decoder) forward, MI355X/gfx950.
// Round 5: latency-bound scans attacked.
//  - enc_scan: ONE block per direction (1024 thr, 16 waves), h-exchange purely
//    in LDS (double-buffered), 1 barrier/step, gate prefetch. No global sync.
//  - dec_scan: 8 blocks, but cross-block exchange now uses relaxed agent-scope
//    sc1 atomics (no buffer_wbl2 / buffer_inv L2 nukes): LDS-staged h ->
//    coalesced 8B sc1 stores -> vmcnt(0) -> relaxed flag -> relaxed 8B loads.
//  - loss_k: one-pass online LSE (halves logits re-read traffic).
// Internal compute: bf16 MFMA, fp32 accumulation. d_out fp32.
// REQUIRES ws_size >= 45,092,864 bytes.
// ---------------------------------------------------------------------------

typedef unsigned short ushort_t;
typedef unsigned int   uint_t;
typedef unsigned long long ull_t;
typedef __attribute__((ext_vector_type(8))) short bf16x8;   // 8 bf16 = 4 VGPRs
typedef __attribute__((ext_vector_type(4))) float f32x4;

#define DEV static __device__ __forceinline__

// problem dims
#define NB 32
#define NS 64
#define NT 48
#define NE 128
#define NH 256
#define ND 512
#define NV 32001

// ws layout (bytes)
#define OFF_GF   0ull          // enc fwd pre-gates [s][1024][32] f32    8 MB
#define OFF_GB   8388608ull    // enc bwd pre-gates                      8 MB
#define OFF_GD   16777216ull   // dec pre-gates     [t][2048][32] f32   12 MB
#define OFF_KP   29360128ull   // key_proj f32 [b*64+s][512]             4 MB
#define OFF_CWO  0ull          // Wo bf16 copy — ALIASES GF..KP, written after attn
#define OFF_QP   33554432ull   // qp f32   [t*32+b][512]                 3 MB
#define OFF_ENC  36700160ull   // enc bf16 [b][s][512]                   2 MB
#define OFF_HBF  38797312ull   // dec h bf16 [t*32+b][512]             1.5 MB
#define OFF_ACTX 40370176ull   // (h+ctx) bf16 [b*48+t][512]           1.5 MB
#define OFF_XEE  41943040ull   // gathered enc embeds bf16 [s*32+b][128] 512 KB
#define OFF_XED  42467328ull   // gathered dec embeds bf16 [t*32+b][128] 384 KB
#define OFF_CWF  42860544ull   // Wih_f bf16 [1024][128]                 256 KB
#define OFF_CWB  43122688ull   // Wih_b bf16                             256 KB
#define OFF_CWD  43384832ull   // Wih_d bf16 [2048][128]                 512 KB
#define OFF_CW1  43909120ull   // W1 bf16 [512][512]                     512 KB
#define OFF_CW2  44433408ull   // W2 bf16                                512 KB
#define OFF_HBE  44957696ull   // (unused now)                            64 KB
#define OFF_HBD  45023232ull   // dec h exchange [par][16384 ush]         64 KB
#define OFF_MISC 45088768ull   // flags(8 int) @0, acc(2 f32) @32
// total: 45,092,864 B

DEV float b2f(ushort_t u) { return __uint_as_float(((uint_t)u) << 16); }
DEV ushort_t f2b(float f) {  // round-to-nearest-even
  uint_t x = __float_as_uint(f);
  return (ushort_t)((x + 0x7fffu + ((x >> 16) & 1u)) >> 16);
}
DEV float fsig(float x) { return 1.f / (1.f + __expf(-x)); }
DEV float ftanh(float x) { float e = __expf(2.f * x); return 1.f - 2.f / (e + 1.f); }

DEV f32x4 mfma16(bf16x8 a, bf16x8 b, f32x4 c) {
  return __builtin_amdgcn_mfma_f32_16x16x32_bf16(a, b, c, 0, 0, 0);
}
DEV void async16(void* lds, const void* g) {
  __builtin_amdgcn_global_load_lds(
      (const __attribute__((address_space(1))) uint_t*)g,
      (__attribute__((address_space(3))) uint_t*)lds, 16, 0, 0);
}
DEV bf16x8 ldw8(const float* p) {  // 8 fp32 -> bf16x8 fragment
  f32x4 a = *(const f32x4*)p;
  f32x4 b = *(const f32x4*)(p + 4);
  bf16x8 r;
  r[0] = (short)f2b(a[0]); r[1] = (short)f2b(a[1]);
  r[2] = (short)f2b(a[2]); r[3] = (short)f2b(a[3]);
  r[4] = (short)f2b(b[0]); r[5] = (short)f2b(b[1]);
  r[6] = (short)f2b(b[2]); r[7] = (short)f2b(b[3]);
  return r;
}

// relaxed agent-scope 8B coherent (sc1) accesses: cross-XCD visible once
// vmcnt retires, never dirties local L2, never triggers wbl2/inv.
DEV void st8_cc(void* p, ull_t v) {
  __hip_atomic_store((ull_t*)p, v, __ATOMIC_RELAXED, __HIP_MEMORY_SCOPE_AGENT);
}
DEV ull_t ld8_cc(const void* p) {
  return __hip_atomic_load((ull_t*)p, __ATOMIC_RELAXED, __HIP_MEMORY_SCOPE_AGENT);
}

__global__ void init_ws(uint_t* misc) {
  for (int i = threadIdx.x; i < 1024; i += 256) misc[i] = 0u;
}

// fp32 -> bf16 converter, 4 elems/thread
__global__ __launch_bounds__(256) void cvt_bf16(const float* __restrict__ src,
                                                ushort_t* __restrict__ dst,
                                                int n4) {
  int i = blockIdx.x * 256 + threadIdx.x;
  if (i < n4) {
    f32x4 x = *(const f32x4*)(src + (size_t)i * 4);
    uint_t lo = ((uint_t)f2b(x[1]) << 16) | (uint_t)f2b(x[0]);
    uint_t hi = ((uint_t)f2b(x[3]) << 16) | (uint_t)f2b(x[2]);
    uint2 v; v.x = lo; v.y = hi;
    *(uint2*)(dst + (size_t)i * 4) = v;
  }
}

// gather embeddings -> compact bf16 A matrices
__global__ __launch_bounds__(128) void gather_enc(const float* __restrict__ emb,
                                                  const int* __restrict__ seq,
                                                  ushort_t* __restrict__ xe) {
  int m = blockIdx.x;                 // m = s*32+b
  int s = m >> 5, b = m & 31;
  int tok = seq[b * NS + s];
  xe[(size_t)m * NE + threadIdx.x] = f2b(emb[(size_t)tok * NE + threadIdx.x]);
}
__global__ __launch_bounds__(128) void gather_dec(const float* __restrict__ emb,
                                                  const int* __restrict__ seq,
                                                  ushort_t* __restrict__ xe) {
  int m = blockIdx.x;                 // m = t*32+b (input shifted right by 1)
  int t = m >> 5, b = m & 31;
  float v = 0.f;
  if (t > 0) v = emb[(size_t)seq[b * NT + t - 1] * NE + threadIdx.x];
  xe[(size_t)m * NE + threadIdx.x] = f2b(v);
}

// ---------------------------------------------------------------------------
// MFMA GEMM-NT: C[m][n] = sum_k A[m][k]*B[n][k] (+fp32 bias). A,B bf16.
// CMODE: 0 f32 [m][n], 1 f32 scan-T [m>>5][n][m&31], 2 f32 [m][NV] with N mask
// ---------------------------------------------------------------------------
template <int CMODE, int BIAS>
__global__ __launch_bounds__(256, 2) void gemm_nt(
    const ushort_t* __restrict__ Abase, const ushort_t* __restrict__ Bmat,
    const float* __restrict__ bias, float* __restrict__ Cf,
    int N, int K, int Nvalid) {
  const int tid = threadIdx.x;
  const int wv = tid >> 6, l = tid & 63, c15 = l & 15, q = l >> 4;
  const int mw = wv >> 1, nw = wv & 1;
  const int n0 = blockIdx.x * 128, m0 = blockIdx.y * 128;
  __shared__ __align__(16) ushort_t lds[32 * 512];  // 16 A slots + 16 B slots

  f32x4 acc[4][4];
  const f32x4 zz = {0.f, 0.f, 0.f, 0.f};
#pragma unroll
  for (int i = 0; i < 4; ++i)
#pragma unroll
    for (int j = 0; j < 4; ++j) acc[i][j] = zz;

  for (int k0 = 0; k0 < K; k0 += 64) {
    __syncthreads();
#pragma unroll
    for (int i = 0; i < 4; ++i) {
      const int slot = wv * 4 + i;
      const int kt = slot >> 3, mt = slot & 7;
      const int m = m0 + mt * 16 + c15;
      async16(&lds[slot * 512], Abase + (size_t)m * K + k0 + kt * 32 + q * 8);
      int n = n0 + mt * 16 + c15;
      if (n >= Nvalid) n = Nvalid - 1;
      async16(&lds[(16 + slot) * 512], Bmat + (size_t)n * K + k0 + kt * 32 + q * 8);
    }
    __syncthreads();  // drains vmcnt for global_load_lds
#pragma unroll
    for (int kt = 0; kt < 2; ++kt) {
      bf16x8 af[4], bfr[4];
#pragma unroll
      for (int i = 0; i < 4; ++i)
        af[i] = *(const bf16x8*)&lds[(kt * 8 + mw * 4 + i) * 512 + l * 8];
#pragma unroll
      for (int i = 0; i < 4; ++i)
        bfr[i] = *(const bf16x8*)&lds[(16 + kt * 8 + nw * 4 + i) * 512 + l * 8];
#pragma unroll
      for (int mi = 0; mi < 4; ++mi)
#pragma unroll
        for (int ni = 0; ni < 4; ++ni)
          acc[mi][ni] = mfma16(af[mi], bfr[ni], acc[mi][ni]);
    }
  }
  // epilogue: D col=lane&15 (n), row=(lane>>4)*4+r (m)   [m89/m91]
#pragma unroll
  for (int mi = 0; mi < 4; ++mi)
#pragma unroll
    for (int ni = 0; ni < 4; ++ni) {
      const int n = n0 + (nw * 4 + ni) * 16 + c15;
      float bv = 0.f;
      if (BIAS) { if (CMODE != 2 || n < Nvalid) bv = bias[n]; }
#pragma unroll
      for (int r = 0; r < 4; ++r) {
        const int m = m0 + (mw * 4 + mi) * 16 + q * 4 + r;
        const float val = acc[mi][ni][r] + bv;
        if (CMODE == 0) Cf[(size_t)m * N + n] = val;
        else if (CMODE == 1) Cf[((size_t)(m >> 5) * N + n) * 32 + (m & 31)] = val;
        else if (n < Nvalid) Cf[(size_t)m * (size_t)NV + n] = val;  // fp32 out
      }
    }
}

// ---------------------------------------------------------------------------
// Encoder scan: ONE block per direction, 1024 thr (16 waves). Lane owns unit
// u=w*16+c for all 4 gates; Whh register-resident (128 VGPR/lane). h-exchange
// is a double-buffered LDS scatter -> 1 __syncthreads per step. Pre-gates for
// step s+1 prefetched into registers during step s MFMA.
// ---------------------------------------------------------------------------
__global__ __launch_bounds__(1024, 1) void enc_scan(
    const float* __restrict__ WhhF, const float* __restrict__ WhhB,
    const float* __restrict__ gF, const float* __restrict__ gB,
    const int* __restrict__ lens, ushort_t* __restrict__ enc_bf) {
  const int tid = threadIdx.x;
  const int d = blockIdx.x;
  const int w = tid >> 6, l = tid & 63, c = l & 15, q = l >> 4;
  const float* Whh = d ? WhhB : WhhF;
  const float* gpre = d ? gB : gF;
  const int u = w * 16 + c;

  bf16x8 wf[4][8];  // [gate][ktile] -> 128 VGPRs
#pragma unroll
  for (int g = 0; g < 4; ++g)
#pragma unroll
    for (int kt = 0; kt < 8; ++kt)
      wf[g][kt] = ldw8(Whh + (size_t)(g * 256 + u) * 256 + kt * 32 + q * 8);

  __shared__ __align__(16) ushort_t hsh[2][8192];  // double-buffered A-frag h
  for (int i = tid; i < 8192; i += 1024) hsh[0][i] = 0;
  float cst[8], hst[8];
#pragma unroll
  for (int i = 0; i < 8; ++i) { cst[i] = 0.f; hst[i] = 0.f; }
  int lensr[8];
#pragma unroll
  for (int mt = 0; mt < 2; ++mt)
#pragma unroll
    for (int r = 0; r < 4; ++r) lensr[mt * 4 + r] = lens[mt * 16 + q * 4 + r];
  const int kt_u = u >> 5, j_u = u & 7, hi16 = ((u >> 3) & 3) << 4;

  // prefetch step-0 pre-gates
  f32x4 gv[4][2];
  {
    const int so0 = d ? 63 : 0;
#pragma unroll
    for (int g = 0; g < 4; ++g) {
      const float* gp = gpre + ((size_t)so0 * 1024 + (g * 256 + u)) * 32 + q * 4;
      gv[g][0] = *(const f32x4*)gp;
      gv[g][1] = *(const f32x4*)(gp + 16);
    }
  }
  __syncthreads();

#pragma unroll 1
  for (int s = 0; s < 64; ++s) {
    const int so = d ? (63 - s) : s;
    const int rb = s & 1;
    f32x4 acc[4][2];
#pragma unroll
    for (int g = 0; g < 4; ++g) { acc[g][0] = gv[g][0]; acc[g][1] = gv[g][1]; }
    if (s < 63) {  // prefetch next step's gates (hides under MFMA)
      const int son = d ? (62 - s) : (s + 1);
#pragma unroll
      for (int g = 0; g < 4; ++g) {
        const float* gp = gpre + ((size_t)son * 1024 + (g * 256 + u)) * 32 + q * 4;
        gv[g][0] = *(const f32x4*)gp;
        gv[g][1] = *(const f32x4*)(gp + 16);
      }
    }
#pragma unroll
    for (int kt = 0; kt < 8; ++kt) {
      bf16x8 a0 = *(const bf16x8*)&hsh[rb][kt * 512 + l * 8];
      bf16x8 a1 = *(const bf16x8*)&hsh[rb][(8 + kt) * 512 + l * 8];
#pragma unroll
      for (int g = 0; g < 4; ++g) {
        acc[g][0] = mfma16(a0, wf[g][kt], acc[g][0]);
        acc[g][1] = mfma16(a1, wf[g][kt], acc[g][1]);
      }
    }
#pragma unroll
    for (int mt = 0; mt < 2; ++mt)
#pragma unroll
      for (int r = 0; r < 4; ++r) {
        const int k8 = mt * 4 + r;
        const int bi = mt * 16 + q * 4 + r;
        float gi = acc[0][mt][r], gf = acc[1][mt][r];
        float gg = acc[2][mt][r], go = acc[3][mt][r];
        float ctn = fsig(gf) * cst[k8] + fsig(gi) * ftanh(gg);
        float hn = fsig(go) * ftanh(ctn);
        bool valid = so < lensr[k8];
        bool upd = (d == 0) || valid;  // fwd: always; bwd: hold when invalid
        cst[k8] = upd ? ctn : cst[k8];
        hst[k8] = upd ? hn : hst[k8];
        enc_bf[((size_t)bi * 64 + so) * 512 + d * 256 + u] = f2b(valid ? hn : 0.f);
        hsh[rb ^ 1][((mt * 8 + kt_u) * 64 + ((bi & 15) | hi16)) * 8 + j_u] =
            f2b(hst[k8]);
      }
    __syncthreads();  // writes of h(s) visible; reads of hsh[rb] all retired
  }
}

// ---------------------------------------------------------------------------
// Decoder scan: 8 blocks x 512 thr. Lane pair (c, c+8) shares unit uu:
// c<8 holds gates (i,g), c>=8 holds (f,o); shfl_xor(8) moves sig(i)*tanh(g).
// Cross-block exchange: h scattered to LDS (next buffer), own 4KB slice copied
// to global with coalesced 8B relaxed-agent (sc1) stores, vmcnt(0) drain,
// relaxed flag add + relaxed poll (no L2 writeback/invalidate!), peers read
// back with relaxed 8B loads into LDS.
// ---------------------------------------------------------------------------
__global__ __launch_bounds__(512, 2) void dec_scan(
    const float* __restrict__ Whh, const float* __restrict__ gpre,
    ushort_t* __restrict__ h_bf, ushort_t* __restrict__ hbuf,
    int* __restrict__ flag) {
  const int tid = threadIdx.x;
  const int bb = blockIdx.x;
  const int w = tid >> 6, l = tid & 63, c = l & 15, q = l >> 4;
  const int uu = bb * 64 + w * 8 + (c & 7);
  const int row0 = ((c >> 3)) * 512 + uu;        // gate i or f
  const int row1 = (2 + (c >> 3)) * 512 + uu;    // gate g or o

  bf16x8 wf0[16], wf1[16];  // 128 VGPRs
#pragma unroll
  for (int kt = 0; kt < 16; ++kt) {
    wf0[kt] = ldw8(Whh + (size_t)row0 * 512 + kt * 32 + q * 8);
    wf1[kt] = ldw8(Whh + (size_t)row1 * 512 + kt * 32 + q * 8);
  }
  __shared__ __align__(16) ushort_t hsh[2][16384];  // double-buffered
  for (int i = tid; i < 16384; i += 512) hsh[0][i] = 0;
  float cst[8];
#pragma unroll
  for (int i = 0; i < 8; ++i) cst[i] = 0.f;
  const int kt_u = uu >> 5, j_u = uu & 7, hi16 = ((uu >> 3) & 3) << 4;

  // prefetch step-0 pre-gates
  f32x4 ga[2], gb[2];
  {
    const float* p0 = gpre + (size_t)row0 * 32 + q * 4;
    const float* p1 = gpre + (size_t)row1 * 32 + q * 4;
    ga[0] = *(const f32x4*)p0; ga[1] = *(const f32x4*)(p0 + 16);
    gb[0] = *(const f32x4*)p1; gb[1] = *(const f32x4*)(p1 + 16);
  }
  __syncthreads();

  int tgt = 0;
#pragma unroll 1
  for (int t = 0; t < 48; ++t) {
    const int rb = t & 1, nb = rb ^ 1;
    f32x4 acc[2][2];
    acc[0][0] = ga[0]; acc[0][1] = ga[1];
    acc[1][0] = gb[0]; acc[1][1] = gb[1];
    if (t < 47) {  // prefetch next step's gates
      const float* p0 = gpre + ((size_t)(t + 1) * 2048 + row0) * 32 + q * 4;
      const float* p1 = gpre + ((size_t)(t + 1) * 2048 + row1) * 32 + q * 4;
      ga[0] = *(const f32x4*)p0; ga[1] = *(const f32x4*)(p0 + 16);
      gb[0] = *(const f32x4*)p1; gb[1] = *(const f32x4*)(p1 + 16);
    }
#pragma unroll
    for (int kt = 0; kt < 16; ++kt) {
      bf16x8 a0 = *(const bf16x8*)&hsh[rb][kt * 512 + l * 8];
      bf16x8 a1 = *(const bf16x8*)&hsh[rb][(16 + kt) * 512 + l * 8];
      acc[0][0] = mfma16(a0, wf0[kt], acc[0][0]);
      acc[0][1] = mfma16(a1, wf0[kt], acc[0][1]);
      acc[1][0] = mfma16(a0, wf1[kt], acc[1][0]);
      acc[1][1] = mfma16(a1, wf1[kt], acc[1][1]);
    }
#pragma unroll
    for (int mt = 0; mt < 2; ++mt)
#pragma unroll
      for (int r = 0; r < 4; ++r) {
        const int k8 = mt * 4 + r;
        const int bi = mt * 16 + q * 4 + r;
        float x0 = acc[0][mt][r];  // i (c<8) / f (c>=8)
        float x1 = acc[1][mt][r];  // g (c<8) / o (c>=8)
        float Av = fsig(x0) * ftanh(x1);       // meaningful on c<8
        float Ar = __shfl_xor(Av, 8, 64);
        if (c >= 8) {
          float ctn = fsig(x0) * cst[k8] + Ar;
          float hn = fsig(x1) * ftanh(ctn);
          cst[k8] = ctn;
          ushort_t hb16 = f2b(hn);
          h_bf[((size_t)t * 32 + bi) * 512 + uu] = hb16;
          hsh[nb][((mt * 16 + kt_u) * 64 + ((bi & 15) | hi16)) * 8 + j_u] = hb16;
        }
      }
    if (t == 47) break;  // last h never feeds another MFMA step
    __syncthreads();     // h(t) own slice complete in LDS[nb]

    ushort_t* hbw = hbuf + nb * 16384;
    {  // own slice LDS -> global: 4 chunks of 1KB, 1x 8B store per thread
      const int chunk = tid >> 7, word = tid & 127;
      const int mt = chunk >> 1, ktl = chunk & 1;
      const size_t off = ((size_t)(mt * 16 + bb * 2 + ktl) * 512) + (size_t)word * 4;
      ull_t v = *(const ull_t*)&hsh[nb][off];
      st8_cc(hbw + off, v);
    }
    asm volatile("s_waitcnt vmcnt(0)" ::: "memory");  // sc1 stores visible
    __syncthreads();
    tgt += 8;
    if (tid == 0) {
      __hip_atomic_fetch_add(flag, 1, __ATOMIC_RELAXED, __HIP_MEMORY_SCOPE_AGENT);
      while (__hip_atomic_load(flag, __ATOMIC_RELAXED, __HIP_MEMORY_SCOPE_AGENT) < tgt)
        __builtin_amdgcn_s_sleep(1);
    }
    __syncthreads();  // all 8 slices visible at coherence point
    {  // all-gather: 8x 8B relaxed loads per thread, then LDS writes
      ull_t tv[8];
#pragma unroll
      for (int j = 0; j < 8; ++j)
        tv[j] = ld8_cc((const ull_t*)hbw + tid + j * 512);
#pragma unroll
      for (int j = 0; j < 8; ++j)
        ((ull_t*)&hsh[nb][0])[tid + j * 512] = tv[j];
    }
    __syncthreads();  // LDS[nb] ready for step t+1
  }
}

// ---------------------------------------------------------------------------
// Batched attention: one block per (b,t). energy->softmax->ctx->actx=h+ctx
// ---------------------------------------------------------------------------
__global__ __launch_bounds__(256) void attn_k(
    const float* __restrict__ qp, const float* __restrict__ kp,
    const ushort_t* __restrict__ enc_bf, const ushort_t* __restrict__ h_bf,
    const float* __restrict__ vvec, const int* __restrict__ lens,
    ushort_t* __restrict__ actx) {
  const int bid = blockIdx.x;
  const int b = bid / NT, t = bid % NT;
  const int tid = threadIdx.x;
  __shared__ float qps[512], vs[512], es[64];
  {
    const float* qrow = qp + ((size_t)t * 32 + b) * 512;
    float2 x = *(const float2*)&qrow[tid * 2];
    qps[tid * 2] = x.x; qps[tid * 2 + 1] = x.y;
    float2 vv = *(const float2*)&vvec[tid * 2];
    vs[tid * 2] = vv.x; vs[tid * 2 + 1] = vv.y;
  }
  __syncthreads();
  const int s = tid >> 2, i = tid & 3;
  const int len = lens[b];
  {
    const float* kr = kp + ((size_t)b * 64 + s) * 512 + i * 128;
    float e = 0.f;
#pragma unroll 8
    for (int k = 0; k < 128; k += 4) {
      f32x4 x = *(const f32x4*)&kr[k];
      const int ko = i * 128 + k;
      e += ftanh(x[0] + qps[ko]) * vs[ko];
      e += ftanh(x[1] + qps[ko + 1]) * vs[ko + 1];
      e += ftanh(x[2] + qps[ko + 2]) * vs[ko + 2];
      e += ftanh(x[3] + qps[ko + 3]) * vs[ko + 3];
    }
    e += __shfl_xor(e, 1, 64);
    e += __shfl_xor(e, 2, 64);
    if (i == 0) es[s] = (s < len) ? e : -1e10f;
  }
  __syncthreads();
  if (tid < 64) {
    float x = es[tid], m = x;
#pragma unroll
    for (int o = 1; o < 64; o <<= 1) m = fmaxf(m, __shfl_xor(m, o, 64));
    float pe = __expf(x - m), sum = pe;
#pragma unroll
    for (int o = 1; o < 64; o <<= 1) sum += __shfl_xor(sum, o, 64);
    es[tid] = pe / sum;
  }
  __syncthreads();
  const int d0 = tid * 2;
  float a0 = 0.f, a1 = 0.f;
  const ushort_t* erow = enc_bf + (size_t)b * 64 * 512 + d0;
#pragma unroll 4
  for (int ss = 0; ss < 64; ++ss) {
    uint_t uv = *(const uint_t*)(erow + (size_t)ss * 512);
    float wgt = es[ss];
    a0 += wgt * b2f((ushort_t)(uv & 0xffff));
    a1 += wgt * b2f((ushort_t)(uv >> 16));
  }
  uint_t hu = *(const uint_t*)(h_bf + ((size_t)t * 32 + b) * 512 + d0);
  float o0 = a0 + b2f((ushort_t)(hu & 0xffff));
  float o1 = a1 + b2f((ushort_t)(hu >> 16));
  uint_t packed = ((uint_t)f2b(o1) << 16) | (uint_t)f2b(o0);
  *(uint_t*)(actx + ((size_t)b * NT + t) * 512 + d0) = packed;
}

// ---------------------------------------------------------------------------
// Loss: per-(b,t) ONE-PASS online log-sum-exp over V + masked NLL accumulation
// ---------------------------------------------------------------------------
__global__ __launch_bounds__(256) void loss_k(const float* __restrict__ outp,
                                              const int* __restrict__ oseq,
                                              float* __restrict__ acc) {
  const int m = blockIdx.x;
  const int b = m / NT, t = m % NT;
  const int tid = threadIdx.x;
  const float* row = outp + (size_t)m * NV;
  __shared__ float redM[4], redS[4];
  float mx = -1e30f, sm = 0.f;
  for (int v = tid; v < NV; v += 256) {
    float x = row[v];
    float m2 = fmaxf(mx, x);
    sm = sm * __expf(mx - m2) + __expf(x - m2);
    mx = m2;
  }
#pragma unroll
  for (int o = 1; o < 64; o <<= 1) {
    float mo = __shfl_xor(mx, o, 64);
    float so = __shfl_xor(sm, o, 64);
    float m2 = fmaxf(mx, mo);
    sm = sm * __expf(mx - m2) + so * __expf(mo - m2);
    mx = m2;
  }
  if ((tid & 63) == 0) { redM[tid >> 6] = mx; redS[tid >> 6] = sm; }
  __syncthreads();
  if (tid == 0) {
    float M = redM[0], S = redS[0];
#pragma unroll
    for (int i = 1; i < 4; ++i) {
      float m2 = fmaxf(M, redM[i]);
      S = S * __expf(M - m2) + redS[i] * __expf(redM[i] - m2);
      M = m2;
    }
    float lse = __logf(S) + M;
    int tok = oseq[b * NT + t];
    float nll = lse - row[tok];
    if (tok != 0) { atomicAdd(&acc[0], nll); atomicAdd(&acc[1], 1.f); }
  }
}

__global__ void finalize_loss(const float* __restrict__ acc,
                              float* __restrict__ outp) {
  if (threadIdx.x == 0)
    outp[(size_t)NB * NT * NV] = acc[0] / fmaxf(acc[1], 1.f);
}

// ---------------------------------------------------------------------------
extern "C" void kernel_launch(void* const* d_in, const int* in_sizes, int n_in,
                              void* d_out, int out_size, void* d_ws,
                              size_t ws_size, hipStream_t stream) {
  (void)in_sizes; (void)n_in; (void)out_size; (void)ws_size;
  const int* in_seq  = (const int*)d_in[0];
  const int* lens    = (const int*)d_in[1];
  const int* out_seq = (const int*)d_in[2];
  const float* emb_src = (const float*)d_in[3];
  const float* Wih_f = (const float*)d_in[4];
  const float* Whh_f = (const float*)d_in[5];
  const float* b_f   = (const float*)d_in[6];
  const float* Wih_b = (const float*)d_in[7];
  const float* Whh_b = (const float*)d_in[8];
  const float* b_b   = (const float*)d_in[9];
  const float* emb_tgt = (const float*)d_in[10];
  const float* Wih_d = (const float*)d_in[11];
  const float* Whh_d = (const float*)d_in[12];
  const float* b_d   = (const float*)d_in[13];
  const float* W1 = (const float*)d_in[14];
  const float* W2 = (const float*)d_in[15];
  const float* vv = (const float*)d_in[16];
  const float* Wo = (const float*)d_in[17];
  const float* bo = (const float*)d_in[18];

  char* ws = (char*)d_ws;
  float* g_fT    = (float*)(ws + OFF_GF);
  float* g_bT    = (float*)(ws + OFF_GB);
  float* g_dT    = (float*)(ws + OFF_GD);
  float* keyp    = (float*)(ws + OFF_KP);
  float* qp      = (float*)(ws + OFF_QP);
  ushort_t* encb = (ushort_t*)(ws + OFF_ENC);
  ushort_t* hbf  = (ushort_t*)(ws + OFF_HBF);
  ushort_t* actx = (ushort_t*)(ws + OFF_ACTX);
  ushort_t* xee  = (ushort_t*)(ws + OFF_XEE);
  ushort_t* xed  = (ushort_t*)(ws + OFF_XED);
  ushort_t* c_wf = (ushort_t*)(ws + OFF_CWF);
  ushort_t* c_wb = (ushort_t*)(ws + OFF_CWB);
  ushort_t* c_wd = (ushort_t*)(ws + OFF_CWD);
  ushort_t* c_w1 = (ushort_t*)(ws + OFF_CW1);
  ushort_t* c_w2 = (ushort_t*)(ws + OFF_CW2);
  ushort_t* c_wo = (ushort_t*)(ws + OFF_CWO);   // aliases GF..KP (phase 2)
  ushort_t* hbd  = (ushort_t*)(ws + OFF_HBD);
  int* flags     = (int*)(ws + OFF_MISC);
  float* accp    = (float*)(ws + OFF_MISC + 32);
  float* outp    = (float*)d_out;               // fp32 output

  init_ws<<<1, 256, 0, stream>>>((uint_t*)(ws + OFF_MISC));
  // compact gathered embeddings (bf16) + small weight conversions
  gather_enc<<<NB * NS, 128, 0, stream>>>(emb_src, in_seq, xee);
  gather_dec<<<NB * NT, 128, 0, stream>>>(emb_tgt, out_seq, xed);
  cvt_bf16<<<128, 256, 0, stream>>>(Wih_f, c_wf, 32768);
  cvt_bf16<<<128, 256, 0, stream>>>(Wih_b, c_wb, 32768);
  cvt_bf16<<<256, 256, 0, stream>>>(Wih_d, c_wd, 65536);
  cvt_bf16<<<256, 256, 0, stream>>>(W1, c_w1, 65536);
  cvt_bf16<<<256, 256, 0, stream>>>(W2, c_w2, 65536);
  // pre-gates: x@Wih^T + b, scan-transposed output
  gemm_nt<1, 1><<<dim3(8, 16), 256, 0, stream>>>(
      xee, c_wf, b_f, g_fT, 1024, 128, 1024);
  gemm_nt<1, 1><<<dim3(8, 16), 256, 0, stream>>>(
      xee, c_wb, b_b, g_bT, 1024, 128, 1024);
  gemm_nt<1, 1><<<dim3(16, 12), 256, 0, stream>>>(
      xed, c_wd, b_d, g_dT, 2048, 128, 2048);
  // encoder bi-LSTM scan: one block per direction, LDS-only exchange
  enc_scan<<<2, 1024, 0, stream>>>(Whh_f, Whh_b, g_fT, g_bT, lens, encb);
  // key_proj = enc @ W1^T
  gemm_nt<0, 0><<<dim3(4, 16), 256, 0, stream>>>(
      encb, c_w1, nullptr, keyp, 512, 512, 512);
  // decoder LSTM scan (relaxed sc1 exchange protocol)
  dec_scan<<<8, 512, 0, stream>>>(Whh_d, g_dT, hbf, hbd, flags + 2);
  // qp = h @ W2^T
  gemm_nt<0, 0><<<dim3(4, 12), 256, 0, stream>>>(
      hbf, c_w2, nullptr, qp, 512, 512, 512);
  // attention + actx = h + ctx
  attn_k<<<NB * NT, 256, 0, stream>>>(qp, keyp, encb, hbf, vv, lens, actx);
  // Wo bf16 copy into the (now dead) pre-gate/key_proj region
  cvt_bf16<<<16001, 256, 0, stream>>>(Wo, c_wo, 4096128);
  // logits = actx @ Wo^T + bo  -> d_out (fp32)
  gemm_nt<2, 1><<<dim3(251, 12), 256, 0, stream>>>(
      actx, c_wo, bo, outp, NV, 512, NV);
  // loss
  loss_k<<<NB * NT, 256, 0, stream>>>(outp, out_seq, accp);
  finalize_loss<<<1, 64, 0, stream>>>(accp, outp);
}

// Round 2
// 1341.123 us; speedup vs baseline: 1.6779x; 1.6779x over previous
//
#include <hip/hip_runtime.h>

// ---------------------------------------------------------------------------
// Seq2Seq (bi-LSTM encoder + attention decoder) forward, MI355X/gfx950.
// Round 6:
//  - enc_scan: BACK to 4 blocks x 512 thr (2/direction; 8 waves -> 2 waves/SIMD
//    -> 256-VGPR budget so the 128-VGPR Whh stays register-resident; the r5
//    1024-thr block capped VGPRs at 64 and spilled weights to scratch).
//    Cross-block exchange now uses the relaxed agent-scope sc1 protocol that
//    fixed dec_scan: LDS-staged h -> coalesced 8B sc1 stores -> vmcnt(0) ->
//    relaxed per-direction flag -> relaxed 8B loads. No L2 wb/inv.
//  - dec_scan: unchanged from r5 (validated, ~100us faster than r4).
//  - loss_k: one-pass online LSE (validated in r5).
// Internal compute: bf16 MFMA, fp32 accumulation. d_out fp32.
// REQUIRES ws_size >= 45,092,864 bytes.
// ---------------------------------------------------------------------------

typedef unsigned short ushort_t;
typedef unsigned int   uint_t;
typedef unsigned long long ull_t;
typedef __attribute__((ext_vector_type(8))) short bf16x8;   // 8 bf16 = 4 VGPRs
typedef __attribute__((ext_vector_type(4))) float f32x4;

#define DEV static __device__ __forceinline__

// problem dims
#define NB 32
#define NS 64
#define NT 48
#define NE 128
#define NH 256
#define ND 512
#define NV 32001

// ws layout (bytes)
#define OFF_GF   0ull          // enc fwd pre-gates [s][1024][32] f32    8 MB
#define OFF_GB   8388608ull    // enc bwd pre-gates                      8 MB
#define OFF_GD   16777216ull   // dec pre-gates     [t][2048][32] f32   12 MB
#define OFF_KP   29360128ull   // key_proj f32 [b*64+s][512]             4 MB
#define OFF_CWO  0ull          // Wo bf16 copy — ALIASES GF..KP, written after attn
#define OFF_QP   33554432ull   // qp f32   [t*32+b][512]                 3 MB
#define OFF_ENC  36700160ull   // enc bf16 [b][s][512]                   2 MB
#define OFF_HBF  38797312ull   // dec h bf16 [t*32+b][512]             1.5 MB
#define OFF_ACTX 40370176ull   // (h+ctx) bf16 [b*48+t][512]           1.5 MB
#define OFF_XEE  41943040ull   // gathered enc embeds bf16 [s*32+b][128] 512 KB
#define OFF_XED  42467328ull   // gathered dec embeds bf16 [t*32+b][128] 384 KB
#define OFF_CWF  42860544ull   // Wih_f bf16 [1024][128]                 256 KB
#define OFF_CWB  43122688ull   // Wih_b bf16                             256 KB
#define OFF_CWD  43384832ull   // Wih_d bf16 [2048][128]                 512 KB
#define OFF_CW1  43909120ull   // W1 bf16 [512][512]                     512 KB
#define OFF_CW2  44433408ull   // W2 bf16                                512 KB
#define OFF_HBE  44957696ull   // enc h exchange [dir][par][8192 ush]     64 KB
#define OFF_HBD  45023232ull   // dec h exchange [par][16384 ush]         64 KB
#define OFF_MISC 45088768ull   // flags: int0 (fwd), int16 (bwd), int32 (dec);
                               // acc(2 f32) at byte 256
// total: 45,092,864 B

DEV float b2f(ushort_t u) { return __uint_as_float(((uint_t)u) << 16); }
DEV ushort_t f2b(float f) {  // round-to-nearest-even
  uint_t x = __float_as_uint(f);
  return (ushort_t)((x + 0x7fffu + ((x >> 16) & 1u)) >> 16);
}
DEV float fsig(float x) { return 1.f / (1.f + __expf(-x)); }
DEV float ftanh(float x) { float e = __expf(2.f * x); return 1.f - 2.f / (e + 1.f); }

DEV f32x4 mfma16(bf16x8 a, bf16x8 b, f32x4 c) {
  return __builtin_amdgcn_mfma_f32_16x16x32_bf16(a, b, c, 0, 0, 0);
}
DEV void async16(void* lds, const void* g) {
  __builtin_amdgcn_global_load_lds(
      (const __attribute__((address_space(1))) uint_t*)g,
      (__attribute__((address_space(3))) uint_t*)lds, 16, 0, 0);
}
DEV bf16x8 ldw8(const float* p) {  // 8 fp32 -> bf16x8 fragment
  f32x4 a = *(const f32x4*)p;
  f32x4 b = *(const f32x4*)(p + 4);
  bf16x8 r;
  r[0] = (short)f2b(a[0]); r[1] = (short)f2b(a[1]);
  r[2] = (short)f2b(a[2]); r[3] = (short)f2b(a[3]);
  r[4] = (short)f2b(b[0]); r[5] = (short)f2b(b[1]);
  r[6] = (short)f2b(b[2]); r[7] = (short)f2b(b[3]);
  return r;
}

// relaxed agent-scope 8B coherent (sc1) accesses: cross-XCD visible once
// vmcnt retires, never dirties local L2, never triggers wbl2/inv.
DEV void st8_cc(void* p, ull_t v) {
  __hip_atomic_store((ull_t*)p, v, __ATOMIC_RELAXED, __HIP_MEMORY_SCOPE_AGENT);
}
DEV ull_t ld8_cc(const void* p) {
  return __hip_atomic_load((ull_t*)p, __ATOMIC_RELAXED, __HIP_MEMORY_SCOPE_AGENT);
}

__global__ void init_ws(uint_t* misc) {
  for (int i = threadIdx.x; i < 1024; i += 256) misc[i] = 0u;
}

// fp32 -> bf16 converter, 4 elems/thread
__global__ __launch_bounds__(256) void cvt_bf16(const float* __restrict__ src,
                                                ushort_t* __restrict__ dst,
                                                int n4) {
  int i = blockIdx.x * 256 + threadIdx.x;
  if (i < n4) {
    f32x4 x = *(const f32x4*)(src + (size_t)i * 4);
    uint_t lo = ((uint_t)f2b(x[1]) << 16) | (uint_t)f2b(x[0]);
    uint_t hi = ((uint_t)f2b(x[3]) << 16) | (uint_t)f2b(x[2]);
    uint2 v; v.x = lo; v.y = hi;
    *(uint2*)(dst + (size_t)i * 4) = v;
  }
}

// gather embeddings -> compact bf16 A matrices
__global__ __launch_bounds__(128) void gather_enc(const float* __restrict__ emb,
                                                  const int* __restrict__ seq,
                                                  ushort_t* __restrict__ xe) {
  int m = blockIdx.x;                 // m = s*32+b
  int s = m >> 5, b = m & 31;
  int tok = seq[b * NS + s];
  xe[(size_t)m * NE + threadIdx.x] = f2b(emb[(size_t)tok * NE + threadIdx.x]);
}
__global__ __launch_bounds__(128) void gather_dec(const float* __restrict__ emb,
                                                  const int* __restrict__ seq,
                                                  ushort_t* __restrict__ xe) {
  int m = blockIdx.x;                 // m = t*32+b (input shifted right by 1)
  int t = m >> 5, b = m & 31;
  float v = 0.f;
  if (t > 0) v = emb[(size_t)seq[b * NT + t - 1] * NE + threadIdx.x];
  xe[(size_t)m * NE + threadIdx.x] = f2b(v);
}

// ---------------------------------------------------------------------------
// MFMA GEMM-NT: C[m][n] = sum_k A[m][k]*B[n][k] (+fp32 bias). A,B bf16.
// CMODE: 0 f32 [m][n], 1 f32 scan-T [m>>5][n][m&31], 2 f32 [m][NV] with N mask
// ---------------------------------------------------------------------------
template <int CMODE, int BIAS>
__global__ __launch_bounds__(256, 2) void gemm_nt(
    const ushort_t* __restrict__ Abase, const ushort_t* __restrict__ Bmat,
    const float* __restrict__ bias, float* __restrict__ Cf,
    int N, int K, int Nvalid) {
  const int tid = threadIdx.x;
  const int wv = tid >> 6, l = tid & 63, c15 = l & 15, q = l >> 4;
  const int mw = wv >> 1, nw = wv & 1;
  const int n0 = blockIdx.x * 128, m0 = blockIdx.y * 128;
  __shared__ __align__(16) ushort_t lds[32 * 512];  // 16 A slots + 16 B slots

  f32x4 acc[4][4];
  const f32x4 zz = {0.f, 0.f, 0.f, 0.f};
#pragma unroll
  for (int i = 0; i < 4; ++i)
#pragma unroll
    for (int j = 0; j < 4; ++j) acc[i][j] = zz;

  for (int k0 = 0; k0 < K; k0 += 64) {
    __syncthreads();
#pragma unroll
    for (int i = 0; i < 4; ++i) {
      const int slot = wv * 4 + i;
      const int kt = slot >> 3, mt = slot & 7;
      const int m = m0 + mt * 16 + c15;
      async16(&lds[slot * 512], Abase + (size_t)m * K + k0 + kt * 32 + q * 8);
      int n = n0 + mt * 16 + c15;
      if (n >= Nvalid) n = Nvalid - 1;
      async16(&lds[(16 + slot) * 512], Bmat + (size_t)n * K + k0 + kt * 32 + q * 8);
    }
    __syncthreads();  // drains vmcnt for global_load_lds
#pragma unroll
    for (int kt = 0; kt < 2; ++kt) {
      bf16x8 af[4], bfr[4];
#pragma unroll
      for (int i = 0; i < 4; ++i)
        af[i] = *(const bf16x8*)&lds[(kt * 8 + mw * 4 + i) * 512 + l * 8];
#pragma unroll
      for (int i = 0; i < 4; ++i)
        bfr[i] = *(const bf16x8*)&lds[(16 + kt * 8 + nw * 4 + i) * 512 + l * 8];
#pragma unroll
      for (int mi = 0; mi < 4; ++mi)
#pragma unroll
        for (int ni = 0; ni < 4; ++ni)
          acc[mi][ni] = mfma16(af[mi], bfr[ni], acc[mi][ni]);
    }
  }
  // epilogue: D col=lane&15 (n), row=(lane>>4)*4+r (m)   [m89/m91]
#pragma unroll
  for (int mi = 0; mi < 4; ++mi)
#pragma unroll
    for (int ni = 0; ni < 4; ++ni) {
      const int n = n0 + (nw * 4 + ni) * 16 + c15;
      float bv = 0.f;
      if (BIAS) { if (CMODE != 2 || n < Nvalid) bv = bias[n]; }
#pragma unroll
      for (int r = 0; r < 4; ++r) {
        const int m = m0 + (mw * 4 + mi) * 16 + q * 4 + r;
        const float val = acc[mi][ni][r] + bv;
        if (CMODE == 0) Cf[(size_t)m * N + n] = val;
        else if (CMODE == 1) Cf[((size_t)(m >> 5) * N + n) * 32 + (m & 31)] = val;
        else if (n < Nvalid) Cf[(size_t)m * (size_t)NV + n] = val;  // fp32 out
      }
    }
}

// ---------------------------------------------------------------------------
// Encoder scan: 4 blocks (dir=bid>>1, half=bid&1) x 512 thr (8 waves).
// Lane owns unit u for all 4 gates (64 Whh rows/wave); Whh register-resident
// (128 VGPRs; 8-wave block = 2 waves/SIMD -> 256-VGPR budget, no spill).
// h-exchange: scatter into double-buffered LDS frag buffer, copy own 8KB
// slice to global via relaxed sc1 8B stores, vmcnt(0), relaxed per-direction
// flag + poll, read peer 8KB back. Gate prefetch hides gpre latency.
// ---------------------------------------------------------------------------
__global__ __launch_bounds__(512, 2) void enc_scan(
    const float* __restrict__ WhhF, const float* __restrict__ WhhB,
    const float* __restrict__ gF, const float* __restrict__ gB,
    const int* __restrict__ lens, ushort_t* __restrict__ enc_bf,
    ushort_t* __restrict__ hbuf, int* __restrict__ flags) {
  const int tid = threadIdx.x;
  const int d = blockIdx.x >> 1, p = blockIdx.x & 1;
  const int w = tid >> 6, l = tid & 63, c = l & 15, q = l >> 4;
  const float* Whh = d ? WhhB : WhhF;
  const float* gpre = d ? gB : gF;
  ushort_t* hb_base = hbuf + (size_t)d * 2 * 8192;
  int* flag = flags + d * 16;   // separate 64B line per direction
  const int u = p * 128 + w * 16 + c;

  bf16x8 wf[4][8];  // [gate][ktile] -> 128 VGPRs, register-resident
#pragma unroll
  for (int g = 0; g < 4; ++g)
#pragma unroll
    for (int kt = 0; kt < 8; ++kt)
      wf[g][kt] = ldw8(Whh + (size_t)(g * 256 + u) * 256 + kt * 32 + q * 8);

  __shared__ __align__(16) ushort_t hsh[2][8192];  // double-buffered A-frag h
  for (int i = tid; i < 8192; i += 512) hsh[0][i] = 0;
  float cst[8], hst[8];
#pragma unroll
  for (int i = 0; i < 8; ++i) { cst[i] = 0.f; hst[i] = 0.f; }
  int lensr[8];
#pragma unroll
  for (int mt = 0; mt < 2; ++mt)
#pragma unroll
    for (int r = 0; r < 4; ++r) lensr[mt * 4 + r] = lens[mt * 16 + q * 4 + r];
  const int kt_u = u >> 5, j_u = u & 7, hi16 = ((u >> 3) & 3) << 4;

  // prefetch step-0 pre-gates
  f32x4 gv[4][2];
  {
    const int so0 = d ? 63 : 0;
#pragma unroll
    for (int g = 0; g < 4; ++g) {
      const float* gp = gpre + ((size_t)so0 * 1024 + (g * 256 + u)) * 32 + q * 4;
      gv[g][0] = *(const f32x4*)gp;
      gv[g][1] = *(const f32x4*)(gp + 16);
    }
  }
  __syncthreads();

  int tgt = 0;
#pragma unroll 1
  for (int s = 0; s < 64; ++s) {
    const int so = d ? (63 - s) : s;
    const int rb = s & 1, nb = rb ^ 1;
    f32x4 acc[4][2];
#pragma unroll
    for (int g = 0; g < 4; ++g) { acc[g][0] = gv[g][0]; acc[g][1] = gv[g][1]; }
    if (s < 63) {  // prefetch next step's gates (hides under MFMA)
      const int son = d ? (62 - s) : (s + 1);
#pragma unroll
      for (int g = 0; g < 4; ++g) {
        const float* gp = gpre + ((size_t)son * 1024 + (g * 256 + u)) * 32 + q * 4;
        gv[g][0] = *(const f32x4*)gp;
        gv[g][1] = *(const f32x4*)(gp + 16);
      }
    }
#pragma unroll
    for (int kt = 0; kt < 8; ++kt) {
      bf16x8 a0 = *(const bf16x8*)&hsh[rb][kt * 512 + l * 8];
      bf16x8 a1 = *(const bf16x8*)&hsh[rb][(8 + kt) * 512 + l * 8];
#pragma unroll
      for (int g = 0; g < 4; ++g) {
        acc[g][0] = mfma16(a0, wf[g][kt], acc[g][0]);
        acc[g][1] = mfma16(a1, wf[g][kt], acc[g][1]);
      }
    }
#pragma unroll
    for (int mt = 0; mt < 2; ++mt)
#pragma unroll
      for (int r = 0; r < 4; ++r) {
        const int k8 = mt * 4 + r;
        const int bi = mt * 16 + q * 4 + r;
        float gi = acc[0][mt][r], gf = acc[1][mt][r];
        float gg = acc[2][mt][r], go = acc[3][mt][r];
        float ctn = fsig(gf) * cst[k8] + fsig(gi) * ftanh(gg);
        float hn = fsig(go) * ftanh(ctn);
        bool valid = so < lensr[k8];
        bool upd = (d == 0) || valid;  // fwd: always; bwd: hold when invalid
        cst[k8] = upd ? ctn : cst[k8];
        hst[k8] = upd ? hn : hst[k8];
        enc_bf[((size_t)bi * 64 + so) * 512 + d * 256 + u] = f2b(valid ? hn : 0.f);
        hsh[nb][((mt * 8 + kt_u) * 64 + ((bi & 15) | hi16)) * 8 + j_u] =
            f2b(hst[k8]);
      }
    if (s == 63) break;  // last h never feeds another step
    __syncthreads();     // own half of hsh[nb] complete

    ushort_t* hbw = hb_base + nb * 8192;
    {  // own slice LDS -> global: 2 chunks of 4KB, 8B sc1 stores
      ull_t* gdst = (ull_t*)hbw;
      const ull_t* lsrc = (const ull_t*)&hsh[nb][0];
#pragma unroll
      for (int mt2 = 0; mt2 < 2; ++mt2) {
        const int base = (mt2 * 8 + 4 * p) * 128;  // ull index
        st8_cc(gdst + base + tid, lsrc[base + tid]);
      }
    }
    asm volatile("s_waitcnt vmcnt(0)" ::: "memory");  // sc1 stores visible
    __syncthreads();
    tgt += 2;
    if (tid == 0) {
      __hip_atomic_fetch_add(flag, 1, __ATOMIC_RELAXED, __HIP_MEMORY_SCOPE_AGENT);
      while (__hip_atomic_load(flag, __ATOMIC_RELAXED, __HIP_MEMORY_SCOPE_AGENT) < tgt)
        __builtin_amdgcn_s_sleep(1);
    }
    __syncthreads();  // both halves visible at coherence point
    {  // peer slice global -> LDS
      const ull_t* gsrc = (const ull_t*)hbw;
#pragma unroll
      for (int mt2 = 0; mt2 < 2; ++mt2) {
        const int base = (mt2 * 8 + 4 * (1 - p)) * 128;
        ull_t v = ld8_cc(gsrc + base + tid);
        ((ull_t*)&hsh[nb][0])[base + tid] = v;
      }
    }
    __syncthreads();  // hsh[nb] ready for step s+1
  }
}

// ---------------------------------------------------------------------------
// Decoder scan: 8 blocks x 512 thr. Lane pair (c, c+8) shares unit uu:
// c<8 holds gates (i,g), c>=8 holds (f,o); shfl_xor(8) moves sig(i)*tanh(g).
// Cross-block exchange: h scattered to LDS (next buffer), own 4KB slice copied
// to global with coalesced 8B relaxed-agent (sc1) stores, vmcnt(0) drain,
// relaxed flag add + relaxed poll (no L2 writeback/invalidate!), peers read
// back with relaxed 8B loads into LDS.
// ---------------------------------------------------------------------------
__global__ __launch_bounds__(512, 2) void dec_scan(
    const float* __restrict__ Whh, const float* __restrict__ gpre,
    ushort_t* __restrict__ h_bf, ushort_t* __restrict__ hbuf,
    int* __restrict__ flag) {
  const int tid = threadIdx.x;
  const int bb = blockIdx.x;
  const int w = tid >> 6, l = tid & 63, c = l & 15, q = l >> 4;
  const int uu = bb * 64 + w * 8 + (c & 7);
  const int row0 = ((c >> 3)) * 512 + uu;        // gate i or f
  const int row1 = (2 + (c >> 3)) * 512 + uu;    // gate g or o

  bf16x8 wf0[16], wf1[16];  // 128 VGPRs
#pragma unroll
  for (int kt = 0; kt < 16; ++kt) {
    wf0[kt] = ldw8(Whh + (size_t)row0 * 512 + kt * 32 + q * 8);
    wf1[kt] = ldw8(Whh + (size_t)row1 * 512 + kt * 32 + q * 8);
  }
  __shared__ __align__(16) ushort_t hsh[2][16384];  // double-buffered
  for (int i = tid; i < 16384; i += 512) hsh[0][i] = 0;
  float cst[8];
#pragma unroll
  for (int i = 0; i < 8; ++i) cst[i] = 0.f;
  const int kt_u = uu >> 5, j_u = uu & 7, hi16 = ((uu >> 3) & 3) << 4;

  // prefetch step-0 pre-gates
  f32x4 ga[2], gb[2];
  {
    const float* p0 = gpre + (size_t)row0 * 32 + q * 4;
    const float* p1 = gpre + (size_t)row1 * 32 + q * 4;
    ga[0] = *(const f32x4*)p0; ga[1] = *(const f32x4*)(p0 + 16);
    gb[0] = *(const f32x4*)p1; gb[1] = *(const f32x4*)(p1 + 16);
  }
  __syncthreads();

  int tgt = 0;
#pragma unroll 1
  for (int t = 0; t < 48; ++t) {
    const int rb = t & 1, nb = rb ^ 1;
    f32x4 acc[2][2];
    acc[0][0] = ga[0]; acc[0][1] = ga[1];
    acc[1][0] = gb[0]; acc[1][1] = gb[1];
    if (t < 47) {  // prefetch next step's gates
      const float* p0 = gpre + ((size_t)(t + 1) * 2048 + row0) * 32 + q * 4;
      const float* p1 = gpre + ((size_t)(t + 1) * 2048 + row1) * 32 + q * 4;
      ga[0] = *(const f32x4*)p0; ga[1] = *(const f32x4*)(p0 + 16);
      gb[0] = *(const f32x4*)p1; gb[1] = *(const f32x4*)(p1 + 16);
    }
#pragma unroll
    for (int kt = 0; kt < 16; ++kt) {
      bf16x8 a0 = *(const bf16x8*)&hsh[rb][kt * 512 + l * 8];
      bf16x8 a1 = *(const bf16x8*)&hsh[rb][(16 + kt) * 512 + l * 8];
      acc[0][0] = mfma16(a0, wf0[kt], acc[0][0]);
      acc[0][1] = mfma16(a1, wf0[kt], acc[0][1]);
      acc[1][0] = mfma16(a0, wf1[kt], acc[1][0]);
      acc[1][1] = mfma16(a1, wf1[kt], acc[1][1]);
    }
#pragma unroll
    for (int mt = 0; mt < 2; ++mt)
#pragma unroll
      for (int r = 0; r < 4; ++r) {
        const int k8 = mt * 4 + r;
        const int bi = mt * 16 + q * 4 + r;
        float x0 = acc[0][mt][r];  // i (c<8) / f (c>=8)
        float x1 = acc[1][mt][r];  // g (c<8) / o (c>=8)
        float Av = fsig(x0) * ftanh(x1);       // meaningful on c<8
        float Ar = __shfl_xor(Av, 8, 64);
        if (c >= 8) {
          float ctn = fsig(x0) * cst[k8] + Ar;
          float hn = fsig(x1) * ftanh(ctn);
          cst[k8] = ctn;
          ushort_t hb16 = f2b(hn);
          h_bf[((size_t)t * 32 + bi) * 512 + uu] = hb16;
          hsh[nb][((mt * 16 + kt_u) * 64 + ((bi & 15) | hi16)) * 8 + j_u] = hb16;
        }
      }
    if (t == 47) break;  // last h never feeds another MFMA step
    __syncthreads();     // h(t) own slice complete in LDS[nb]

    ushort_t* hbw = hbuf + nb * 16384;
    {  // own slice LDS -> global: 4 chunks of 1KB, 1x 8B store per thread
      const int chunk = tid >> 7, word = tid & 127;
      const int mt = chunk >> 1, ktl = chunk & 1;
      const size_t off = ((size_t)(mt * 16 + bb * 2 + ktl) * 512) + (size_t)word * 4;
      ull_t v = *(const ull_t*)&hsh[nb][off];
      st8_cc(hbw + off, v);
    }
    asm volatile("s_waitcnt vmcnt(0)" ::: "memory");  // sc1 stores visible
    __syncthreads();
    tgt += 8;
    if (tid == 0) {
      __hip_atomic_fetch_add(flag, 1, __ATOMIC_RELAXED, __HIP_MEMORY_SCOPE_AGENT);
      while (__hip_atomic_load(flag, __ATOMIC_RELAXED, __HIP_MEMORY_SCOPE_AGENT) < tgt)
        __builtin_amdgcn_s_sleep(1);
    }
    __syncthreads();  // all 8 slices visible at coherence point
    {  // all-gather: 8x 8B relaxed loads per thread, then LDS writes
      ull_t tv[8];
#pragma unroll
      for (int j = 0; j < 8; ++j)
        tv[j] = ld8_cc((const ull_t*)hbw + tid + j * 512);
#pragma unroll
      for (int j = 0; j < 8; ++j)
        ((ull_t*)&hsh[nb][0])[tid + j * 512] = tv[j];
    }
    __syncthreads();  // LDS[nb] ready for step t+1
  }
}

// ---------------------------------------------------------------------------
// Batched attention: one block per (b,t). energy->softmax->ctx->actx=h+ctx
// ---------------------------------------------------------------------------
__global__ __launch_bounds__(256) void attn_k(
    const float* __restrict__ qp, const float* __restrict__ kp,
    const ushort_t* __restrict__ enc_bf, const ushort_t* __restrict__ h_bf,
    const float* __restrict__ vvec, const int* __restrict__ lens,
    ushort_t* __restrict__ actx) {
  const int bid = blockIdx.x;
  const int b = bid / NT, t = bid % NT;
  const int tid = threadIdx.x;
  __shared__ float qps[512], vs[512], es[64];
  {
    const float* qrow = qp + ((size_t)t * 32 + b) * 512;
    float2 x = *(const float2*)&qrow[tid * 2];
    qps[tid * 2] = x.x; qps[tid * 2 + 1] = x.y;
    float2 vv = *(const float2*)&vvec[tid * 2];
    vs[tid * 2] = vv.x; vs[tid * 2 + 1] = vv.y;
  }
  __syncthreads();
  const int s = tid >> 2, i = tid & 3;
  const int len = lens[b];
  {
    const float* kr = kp + ((size_t)b * 64 + s) * 512 + i * 128;
    float e = 0.f;
#pragma unroll 8
    for (int k = 0; k < 128; k += 4) {
      f32x4 x = *(const f32x4*)&kr[k];
      const int ko = i * 128 + k;
      e += ftanh(x[0] + qps[ko]) * vs[ko];
      e += ftanh(x[1] + qps[ko + 1]) * vs[ko + 1];
      e += ftanh(x[2] + qps[ko + 2]) * vs[ko + 2];
      e += ftanh(x[3] + qps[ko + 3]) * vs[ko + 3];
    }
    e += __shfl_xor(e, 1, 64);
    e += __shfl_xor(e, 2, 64);
    if (i == 0) es[s] = (s < len) ? e : -1e10f;
  }
  __syncthreads();
  if (tid < 64) {
    float x = es[tid], m = x;
#pragma unroll
    for (int o = 1; o < 64; o <<= 1) m = fmaxf(m, __shfl_xor(m, o, 64));
    float pe = __expf(x - m), sum = pe;
#pragma unroll
    for (int o = 1; o < 64; o <<= 1) sum += __shfl_xor(sum, o, 64);
    es[tid] = pe / sum;
  }
  __syncthreads();
  const int d0 = tid * 2;
  float a0 = 0.f, a1 = 0.f;
  const ushort_t* erow = enc_bf + (size_t)b * 64 * 512 + d0;
#pragma unroll 4
  for (int ss = 0; ss < 64; ++ss) {
    uint_t uv = *(const uint_t*)(erow + (size_t)ss * 512);
    float wgt = es[ss];
    a0 += wgt * b2f((ushort_t)(uv & 0xffff));
    a1 += wgt * b2f((ushort_t)(uv >> 16));
  }
  uint_t hu = *(const uint_t*)(h_bf + ((size_t)t * 32 + b) * 512 + d0);
  float o0 = a0 + b2f((ushort_t)(hu & 0xffff));
  float o1 = a1 + b2f((ushort_t)(hu >> 16));
  uint_t packed = ((uint_t)f2b(o1) << 16) | (uint_t)f2b(o0);
  *(uint_t*)(actx + ((size_t)b * NT + t) * 512 + d0) = packed;
}

// ---------------------------------------------------------------------------
// Loss: per-(b,t) ONE-PASS online log-sum-exp over V + masked NLL accumulation
// ---------------------------------------------------------------------------
__global__ __launch_bounds__(256) void loss_k(const float* __restrict__ outp,
                                              const int* __restrict__ oseq,
                                              float* __restrict__ acc) {
  const int m = blockIdx.x;
  const int b = m / NT, t = m % NT;
  const int tid = threadIdx.x;
  const float* row = outp + (size_t)m * NV;
  __shared__ float redM[4], redS[4];
  float mx = -1e30f, sm = 0.f;
  for (int v = tid; v < NV; v += 256) {
    float x = row[v];
    float m2 = fmaxf(mx, x);
    sm = sm * __expf(mx - m2) + __expf(x - m2);
    mx = m2;
  }
#pragma unroll
  for (int o = 1; o < 64; o <<= 1) {
    float mo = __shfl_xor(mx, o, 64);
    float so = __shfl_xor(sm, o, 64);
    float m2 = fmaxf(mx, mo);
    sm = sm * __expf(mx - m2) + so * __expf(mo - m2);
    mx = m2;
  }
  if ((tid & 63) == 0) { redM[tid >> 6] = mx; redS[tid >> 6] = sm; }
  __syncthreads();
  if (tid == 0) {
    float M = redM[0], S = redS[0];
#pragma unroll
    for (int i = 1; i < 4; ++i) {
      float m2 = fmaxf(M, redM[i]);
      S = S * __expf(M - m2) + redS[i] * __expf(redM[i] - m2);
      M = m2;
    }
    float lse = __logf(S) + M;
    int tok = oseq[b * NT + t];
    float nll = lse - row[tok];
    if (tok != 0) { atomicAdd(&acc[0], nll); atomicAdd(&acc[1], 1.f); }
  }
}

__global__ void finalize_loss(const float* __restrict__ acc,
                              float* __restrict__ outp) {
  if (threadIdx.x == 0)
    outp[(size_t)NB * NT * NV] = acc[0] / fmaxf(acc[1], 1.f);
}

// ---------------------------------------------------------------------------
extern "C" void kernel_launch(void* const* d_in, const int* in_sizes, int n_in,
                              void* d_out, int out_size, void* d_ws,
                              size_t ws_size, hipStream_t stream) {
  (void)in_sizes; (void)n_in; (void)out_size; (void)ws_size;
  const int* in_seq  = (const int*)d_in[0];
  const int* lens    = (const int*)d_in[1];
  const int* out_seq = (const int*)d_in[2];
  const float* emb_src = (const float*)d_in[3];
  const float* Wih_f = (const float*)d_in[4];
  const float* Whh_f = (const float*)d_in[5];
  const float* b_f   = (const float*)d_in[6];
  const float* Wih_b = (const float*)d_in[7];
  const float* Whh_b = (const float*)d_in[8];
  const float* b_b   = (const float*)d_in[9];
  const float* emb_tgt = (const float*)d_in[10];
  const float* Wih_d = (const float*)d_in[11];
  const float* Whh_d = (const float*)d_in[12];
  const float* b_d   = (const float*)d_in[13];
  const float* W1 = (const float*)d_in[14];
  const float* W2 = (const float*)d_in[15];
  const float* vv = (const float*)d_in[16];
  const float* Wo = (const float*)d_in[17];
  const float* bo = (const float*)d_in[18];

  char* ws = (char*)d_ws;
  float* g_fT    = (float*)(ws + OFF_GF);
  float* g_bT    = (float*)(ws + OFF_GB);
  float* g_dT    = (float*)(ws + OFF_GD);
  float* keyp    = (float*)(ws + OFF_KP);
  float* qp      = (float*)(ws + OFF_QP);
  ushort_t* encb = (ushort_t*)(ws + OFF_ENC);
  ushort_t* hbf  = (ushort_t*)(ws + OFF_HBF);
  ushort_t* actx = (ushort_t*)(ws + OFF_ACTX);
  ushort_t* xee  = (ushort_t*)(ws + OFF_XEE);
  ushort_t* xed  = (ushort_t*)(ws + OFF_XED);
  ushort_t* c_wf = (ushort_t*)(ws + OFF_CWF);
  ushort_t* c_wb = (ushort_t*)(ws + OFF_CWB);
  ushort_t* c_wd = (ushort_t*)(ws + OFF_CWD);
  ushort_t* c_w1 = (ushort_t*)(ws + OFF_CW1);
  ushort_t* c_w2 = (ushort_t*)(ws + OFF_CW2);
  ushort_t* c_wo = (ushort_t*)(ws + OFF_CWO);   // aliases GF..KP (phase 2)
  ushort_t* hbe  = (ushort_t*)(ws + OFF_HBE);
  ushort_t* hbd  = (ushort_t*)(ws + OFF_HBD);
  int* flags     = (int*)(ws + OFF_MISC);
  float* accp    = (float*)(ws + OFF_MISC + 256);
  float* outp    = (float*)d_out;               // fp32 output

  init_ws<<<1, 256, 0, stream>>>((uint_t*)(ws + OFF_MISC));
  // compact gathered embeddings (bf16) + small weight conversions
  gather_enc<<<NB * NS, 128, 0, stream>>>(emb_src, in_seq, xee);
  gather_dec<<<NB * NT, 128, 0, stream>>>(emb_tgt, out_seq, xed);
  cvt_bf16<<<128, 256, 0, stream>>>(Wih_f, c_wf, 32768);
  cvt_bf16<<<128, 256, 0, stream>>>(Wih_b, c_wb, 32768);
  cvt_bf16<<<256, 256, 0, stream>>>(Wih_d, c_wd, 65536);
  cvt_bf16<<<256, 256, 0, stream>>>(W1, c_w1, 65536);
  cvt_bf16<<<256, 256, 0, stream>>>(W2, c_w2, 65536);
  // pre-gates: x@Wih^T + b, scan-transposed output
  gemm_nt<1, 1><<<dim3(8, 16), 256, 0, stream>>>(
      xee, c_wf, b_f, g_fT, 1024, 128, 1024);
  gemm_nt<1, 1><<<dim3(8, 16), 256, 0, stream>>>(
      xee, c_wb, b_b, g_bT, 1024, 128, 1024);
  gemm_nt<1, 1><<<dim3(16, 12), 256, 0, stream>>>(
      xed, c_wd, b_d, g_dT, 2048, 128, 2048);
  // encoder bi-LSTM scan (relaxed sc1 exchange protocol)
  enc_scan<<<4, 512, 0, stream>>>(Whh_f, Whh_b, g_fT, g_bT, lens, encb, hbe,
                                  flags);
  // key_proj = enc @ W1^T
  gemm_nt<0, 0><<<dim3(4, 16), 256, 0, stream>>>(
      encb, c_w1, nullptr, keyp, 512, 512, 512);
  // decoder LSTM scan (relaxed sc1 exchange protocol)
  dec_scan<<<8, 512, 0, stream>>>(Whh_d, g_dT, hbf, hbd, flags + 32);
  // qp = h @ W2^T
  gemm_nt<0, 0><<<dim3(4, 12), 256, 0, stream>>>(
      hbf, c_w2, nullptr, qp, 512, 512, 512);
  // attention + actx = h + ctx
  attn_k<<<NB * NT, 256, 0, stream>>>(qp, keyp, encb, hbf, vv, lens, actx);
  // Wo bf16 copy into the (now dead) pre-gate/key_proj region
  cvt_bf16<<<16001, 256, 0, stream>>>(Wo, c_wo, 4096128);
  // logits = actx @ Wo^T + bo  -> d_out (fp32)
  gemm_nt<2, 1><<<dim3(251, 12), 256, 0, stream>>>(
      actx, c_wo, bo, outp, NV, 512, NV);
  // loss
  loss_k<<<NB * NT, 256, 0, stream>>>(outp, out_seq, accp);
  finalize_loss<<<1, 64, 0, stream>>>(accp, outp);
}